// Round 15
// baseline (133.233 us; speedup 1.0000x reference)
//
#include <hip/hip_runtime.h>

#define BB 16
#define SS 2048
#define DD 128
// exp(s/sqrt(128)) = 2^(s * CE),  CE = log2(e)/sqrt(128)
#define CE (0.08838834764831845f * 1.4426950408889634f)

typedef __attribute__((ext_vector_type(4))) float f32x4;
typedef __attribute__((ext_vector_type(8))) short short8;
typedef __attribute__((ext_vector_type(4))) unsigned short us4;
typedef __attribute__((ext_vector_type(8))) unsigned short us8;

__device__ inline unsigned short f2bf(float f) {
    unsigned u = __float_as_uint(f);
    u += 0x7fffu + ((u >> 16) & 1u);   // round-to-nearest-even
    return (unsigned short)(u >> 16);
}

// XOR swizzles (swzA: 256B rows; swzB: 128B rows)
__device__ inline int swzA(int row, int col) {
    int byteoff = (row << 8) + ((col >> 3) << 4);
    byteoff ^= (row & 7) << 4;
    return (byteoff >> 1) + (col & 7);
}
__device__ inline int swzB(int row, int col) {
    int byteoff = (row << 7) + ((col >> 3) << 4);
    byteoff ^= (row & 7) << 4;
    return (byteoff >> 1) + (col & 7);
}

// ---------------------------------------------------------------------------
// prep: K fp32 -> bf16 Kb; V fp32 -> VT (b,d,k) bf16; mask -> additive fp32.
// (unchanged from r14 — proven)
// ---------------------------------------------------------------------------
__global__ __launch_bounds__(256) void prep_kernel(
    const float* __restrict__ K, const float* __restrict__ V,
    const int* __restrict__ mask,
    unsigned short* __restrict__ Kb, unsigned short* __restrict__ VT,
    float* __restrict__ maskAdd)
{
    __shared__ unsigned short tile[64 * 136];
    int b = blockIdx.y, k0 = blockIdx.x << 6;
    int t = threadIdx.x;
    const size_t base = ((size_t)b * SS + k0) * DD;   // 8192 elements

    for (int i = 0; i < 8; ++i) {
        int f4 = (i << 8) + t;
        f32x4 k = reinterpret_cast<const f32x4*>(K + base)[f4];
        us4 kh;
        for (int j = 0; j < 4; ++j) kh[j] = f2bf(k[j]);
        reinterpret_cast<us4*>(Kb + base)[f4] = kh;
    }
    if (t < 64)
        maskAdd[(size_t)b * SS + k0 + t] =
            mask[(size_t)b * SS + k0 + t] ? 0.0f : __int_as_float(0xff800000);

    for (int i = 0; i < 8; ++i) {
        int f4 = (i << 8) + t;
        int k  = f4 >> 5;
        int n  = (f4 & 31) << 2;
        f32x4 v = reinterpret_cast<const f32x4*>(V + base)[f4];
        us4 h;
        for (int j = 0; j < 4; ++j) h[j] = f2bf(v[j]);
        *reinterpret_cast<us4*>(&tile[k * 136 + n]) = h;
    }
    __syncthreads();
    unsigned short* outp = VT + (size_t)b * DD * SS;
    for (int i = 0; i < 4; ++i) {
        int id = (i << 8) + t;
        int n  = id >> 3;
        int c8 = id & 7;
        us8 o;
        for (int j = 0; j < 8; ++j) o[j] = tile[((c8 << 3) + j) * 136 + n];
        *reinterpret_cast<us8*>(&outp[(size_t)n * SS + k0 + (c8 << 3)]) = o;
    }
}

// ---------------------------------------------------------------------------
// fused16: block = (b, 64 q-rows), full KV. 512 thr = 8 waves in 4x2 (wq,wkv):
// wave owns 16 q x 32-kv-half of each 64-kv tile. grid 512 = 2 blocks/CU
// (launch_bounds(512,4), LDS 72.5 KB) -> phase-skewed blocks overlap pass-A
// compute with pass-B store stream. qf reused across both passes.
// ---------------------------------------------------------------------------
__global__ __launch_bounds__(512, 4) void fused16_kernel(
    const float* __restrict__ Qf, const unsigned short* __restrict__ Kb,
    const unsigned short* __restrict__ VT, const float* __restrict__ maskAdd,
    float* __restrict__ O, float* __restrict__ P)
{
    __shared__ unsigned short Ks[2][64 * 128];    // 32 KB (reused as xch floats)
    __shared__ unsigned short VTs[2][128 * 64];   // 32 KB
    __shared__ unsigned short Ps[4 * 1024];       // 8 KB: per-wq 16r x 64c
    __shared__ float Lhalf[4][16];
    __shared__ float Larr[64];

    const int id = blockIdx.x;                    // grid 512
    const int xcd = id & 7, j = id >> 3;          // j in 0..63
    const int b   = (xcd << 1) | (j >> 5);
    const int q0  = (j & 31) << 6;                // 64-row q panel

    const int t = threadIdx.x, lane = t & 63, w = t >> 6;
    const int wq = w >> 1, wkv = w & 1;
    const int lr = lane & 15, lg = lane >> 4;

    const unsigned short* Kbb = Kb + (size_t)b * SS * DD;
    const unsigned short* Vbb = VT + (size_t)b * DD * SS;
    const float* Mb = maskAdd + (size_t)b * SS;

    // Q fragments (B-operand), q = q0 + wq*16 + lr — used by BOTH passes
    const float* Qp = Qf + ((size_t)b * SS + q0 + wq * 16 + lr) * DD;
    short8 qf[4];
    for (int kb = 0; kb < 4; ++kb) {
        const float* p = Qp + kb * 32 + lg * 8;
        f32x4 a0 = *reinterpret_cast<const f32x4*>(p);
        f32x4 a1 = *(reinterpret_cast<const f32x4*>(p) + 1);
        short8 s;
        for (int jj = 0; jj < 4; ++jj) { s[jj] = (short)f2bf(a0[jj]); s[4 + jj] = (short)f2bf(a1[jj]); }
        qf[kb] = s;
    }

    f32x4 oacc[8] = {};
    float rsum = 0.f;
    unsigned short* Pwq = &Ps[wq * 1024];   // shared by the wkv pair (disjoint col halves)

    us8 kstg[2], vstg[2];
#define LOADTILE(kv)                                                             \
    for (int i = 0; i < 2; ++i) {                                                \
        int f = i * 512 + t;                                                     \
        kstg[i] = *reinterpret_cast<const us8*>(                                 \
            Kbb + (size_t)((kv) + (f >> 4)) * DD + ((f & 15) << 3));             \
        vstg[i] = *reinterpret_cast<const us8*>(                                 \
            Vbb + (size_t)(f >> 3) * SS + (kv) + ((f & 7) << 3));                \
    }
#define WRITETILE(bf)                                                            \
    for (int i = 0; i < 2; ++i) {                                                \
        int f = i * 512 + t;                                                     \
        *reinterpret_cast<us8*>(&Ks[bf][swzA(f >> 4, (f & 15) << 3)]) = kstg[i]; \
        *reinterpret_cast<us8*>(&VTs[bf][swzB(f >> 3, (f & 7) << 3)]) = vstg[i]; \
    }
#define LOADK(kv)                                                                \
    for (int i = 0; i < 2; ++i) {                                                \
        int f = i * 512 + t;                                                     \
        kstg[i] = *reinterpret_cast<const us8*>(                                 \
            Kbb + (size_t)((kv) + (f >> 4)) * DD + ((f & 15) << 3));             \
    }
#define WRITEK(bf)                                                               \
    for (int i = 0; i < 2; ++i) {                                                \
        int f = i * 512 + t;                                                     \
        *reinterpret_cast<us8*>(&Ks[bf][swzA(f >> 4, (f & 15) << 3)]) = kstg[i]; \
    }

    // ---------------- pass A ----------------
    LOADTILE(0);
    WRITETILE(0);

    for (int kt = 0; kt < 32; ++kt) {
        const int cur = kt & 1;
        const int kv0 = kt << 6;
        if (kt + 1 < 32) { LOADTILE(kv0 + 64); }   // T14
        __syncthreads();                           // buf[cur] visible

        // S^T half: rows kv = wkv*32 + n*16 + lg*4 + r, cols q = lr
        f32x4 sacc[2] = {};
        __builtin_amdgcn_s_setprio(1);
        for (int kb = 0; kb < 4; ++kb) {
            short8 kf[2];
            for (int n = 0; n < 2; ++n)
                kf[n] = *reinterpret_cast<const short8*>(
                    &Ks[cur][swzA(wkv * 32 + n * 16 + lr, kb * 32 + lg * 8)]);
            for (int n = 0; n < 2; ++n)
                sacc[n] = __builtin_amdgcn_mfma_f32_16x16x32_bf16(
                    kf[n], qf[kb], sacc[n], 0, 0, 0);
        }
        __builtin_amdgcn_s_setprio(0);

        // p = 2^(s*CE + ma); rowsum; stash P[q=lr][kv_local] in wq region
        for (int n = 0; n < 2; ++n) {
            f32x4 ma = *reinterpret_cast<const f32x4*>(
                Mb + kv0 + wkv * 32 + n * 16 + lg * 4);
            us4 hh;
            for (int r = 0; r < 4; ++r) {
                float p = __builtin_amdgcn_exp2f(fmaf(sacc[n][r], CE, ma[r]));
                rsum += p;
                hh[r] = f2bf(p);
            }
            *reinterpret_cast<us4*>(&Pwq[swzB(lr, wkv * 32 + n * 16 + lg * 4)]) = hh;
        }
        asm volatile("s_waitcnt lgkmcnt(0)" ::: "memory");
        __builtin_amdgcn_sched_barrier(0);

        // PV over this wave's 32-kv half (K=32 step)
        short8 pf = *reinterpret_cast<const short8*>(
            &Pwq[swzB(lr, wkv * 32 + lg * 8)]);
        __builtin_amdgcn_s_setprio(1);
        for (int nd = 0; nd < 8; ++nd) {
            short8 vf = *reinterpret_cast<const short8*>(
                &VTs[cur][swzB(nd * 16 + lr, wkv * 32 + lg * 8)]);
            oacc[nd] = __builtin_amdgcn_mfma_f32_16x16x32_bf16(pf, vf, oacc[nd], 0, 0, 0);
        }
        __builtin_amdgcn_s_setprio(0);

        if (kt + 1 < 32) { WRITETILE(cur ^ 1); }   // readers passed top barrier
    }

    // ---------------- epilogue: wkv-pair reduce + O write ----------------
    rsum += __shfl_xor(rsum, 16, 64);   // sum over lg groups (q = lr)
    rsum += __shfl_xor(rsum, 32, 64);
    __syncthreads();                    // pass A fully done; Ks reusable as xch

    float* xch = reinterpret_cast<float*>(&Ks[0][0]);   // 8192 floats = 32 KB
    if (wkv == 1) {
        if (lg == 0) Lhalf[wq][lr] = rsum;
        for (int nd = 0; nd < 8; ++nd)
            for (int r = 0; r < 4; ++r)
                xch[wq * 2048 + (lg * 4 + r) * 128 + nd * 16 + lr] = oacc[nd][r];
    }
    __syncthreads();
    if (wkv == 0) {
        float L = rsum + Lhalf[wq][lr];
        if (lg == 0) Larr[wq * 16 + lr] = L;
        for (int nd = 0; nd < 8; ++nd)
            for (int r = 0; r < 4; ++r)
                oacc[nd][r] += xch[wq * 2048 + (lg * 4 + r) * 128 + nd * 16 + lr];
    }
    __syncthreads();   // Larr visible; xch reads done -> Ks free

    LOADK(0);          // issue early; hides under O write
    if (wkv == 0) {
        f32x4 inv;
        for (int r = 0; r < 4; ++r) {
            float L = Larr[wq * 16 + lg * 4 + r];
            inv[r] = L > 0.f ? 1.f / L : 0.f;
        }
        float* Og = O + ((size_t)b * SS + q0 + wq * 16) * DD;
        for (int nd = 0; nd < 8; ++nd)
            for (int r = 0; r < 4; ++r)
                Og[(size_t)(lg * 4 + r) * DD + nd * 16 + lr] = oacc[nd][r] * inv[r];
    }
    float Lq = Larr[wq * 16 + lr];
    const float lil = Lq > 0.f ? -__builtin_amdgcn_logf(Lq)
                               : __int_as_float(0xff800000);

    // ---------------- pass B ----------------
    WRITEK(0);

    for (int kt = 0; kt < 32; ++kt) {
        const int cur = kt & 1;
        const int kv0 = kt << 6;
        if (kt + 1 < 32) { LOADK(kv0 + 64); }
        __syncthreads();

        // identical per-(q,kv) kb-chain as pass A -> bit-identical S
        f32x4 sacc2[2] = {};
        for (int kb = 0; kb < 4; ++kb) {
            short8 kf[2];
            for (int n = 0; n < 2; ++n)
                kf[n] = *reinterpret_cast<const short8*>(
                    &Ks[cur][swzA(wkv * 32 + n * 16 + lr, kb * 32 + lg * 8)]);
            for (int n = 0; n < 2; ++n)
                sacc2[n] = __builtin_amdgcn_mfma_f32_16x16x32_bf16(
                    kf[n], qf[kb], sacc2[n], 0, 0, 0);
        }

        float* Pp = P + ((size_t)b * SS + q0 + wq * 16 + lr) * SS + kv0 + wkv * 32;
        for (int n = 0; n < 2; ++n) {
            f32x4 ma = *reinterpret_cast<const f32x4*>(
                Mb + kv0 + wkv * 32 + n * 16 + lg * 4);
            f32x4 out;
            for (int r = 0; r < 4; ++r)
                out[r] = __builtin_amdgcn_exp2f(fmaf(sacc2[n][r], CE, ma[r]) + lil);
            *reinterpret_cast<f32x4*>(Pp + n * 16 + lg * 4) = out;
        }

        if (kt + 1 < 32) { WRITEK(cur ^ 1); }
    }
#undef LOADTILE
#undef WRITETILE
#undef LOADK
#undef WRITEK
}

// ---------------------------------------------------------------------------
// Fallback pipeline (no workspace requirements)
// ---------------------------------------------------------------------------
__global__ __launch_bounds__(256) void qk_exp_kernel(
    const float* __restrict__ Q, const float* __restrict__ Kin,
    const int* __restrict__ mask, float* __restrict__ P)
{
    __shared__ unsigned short Qs[128 * 128];
    __shared__ unsigned short Ks[128 * 128];
    const int b  = blockIdx.z;
    const int m0 = blockIdx.y << 7;
    const int n0 = blockIdx.x << 7;
    const int t  = threadIdx.x;
    const float* Qp = Q   + ((size_t)b * SS + m0) * DD;
    const float* Kp = Kin + ((size_t)b * SS + n0) * DD;
    for (int i = 0; i < 16; ++i) {
        int f4  = (i << 8) + t;
        int row = f4 >> 5;
        int col = (f4 & 31) << 2;
        f32x4 q = reinterpret_cast<const f32x4*>(Qp)[f4];
        f32x4 k = reinterpret_cast<const f32x4*>(Kp)[f4];
        us4 qh, kh;
        for (int jj = 0; jj < 4; ++jj) { qh[jj] = f2bf(q[jj]); kh[jj] = f2bf(k[jj]); }
        *reinterpret_cast<us4*>(&Qs[swzA(row, col)]) = qh;
        *reinterpret_cast<us4*>(&Ks[swzA(row, col)]) = kh;
    }
    __syncthreads();
    const int lane = t & 63, wid = t >> 6;
    const int wr = wid >> 1, wc = wid & 1;
    const int lr = lane & 15, lg = lane >> 4;
    f32x4 acc[4][4] = {};
    for (int kb = 0; kb < 4; ++kb) {
        short8 a[4], bq[4];
        int kcol = (kb << 5) + (lg << 3);
        for (int m = 0; m < 4; ++m)
            a[m] = *reinterpret_cast<const short8*>(&Qs[swzA((wr << 6) + (m << 4) + lr, kcol)]);
        for (int n = 0; n < 4; ++n)
            bq[n] = *reinterpret_cast<const short8*>(&Ks[swzA((wc << 6) + (n << 4) + lr, kcol)]);
        for (int m = 0; m < 4; ++m)
            for (int n = 0; n < 4; ++n)
                acc[m][n] = __builtin_amdgcn_mfma_f32_16x16x32_bf16(a[m], bq[n], acc[m][n], 0, 0, 0);
    }
    const int* am = mask + (size_t)b * SS;
    for (int n = 0; n < 4; ++n) {
        int col = n0 + (wc << 6) + (n << 4) + lr;
        bool allow = am[col] != 0;
        for (int m = 0; m < 4; ++m) {
            int rowb = m0 + (wr << 6) + (m << 4) + (lg << 2);
            float* Pp = P + ((size_t)b * SS + rowb) * SS + col;
            for (int r = 0; r < 4; ++r) {
                float p = allow ? __expf(acc[m][n][r] * 0.08838834764831845f) : 0.0f;
                Pp[(size_t)r * SS] = p;
            }
        }
    }
}

__global__ __launch_bounds__(256) void norm_kernel(float* __restrict__ P)
{
    int row  = (blockIdx.x << 2) + (threadIdx.x >> 6);
    int lane = threadIdx.x & 63;
    float* Pr = P + (size_t)row * SS;
    f32x4 v[8];
    float sum = 0.f;
    for (int i = 0; i < 8; ++i) {
        v[i] = reinterpret_cast<f32x4*>(Pr)[(i << 6) + lane];
        sum += v[i][0] + v[i][1] + v[i][2] + v[i][3];
    }
    for (int off = 1; off < 64; off <<= 1) sum += __shfl_xor(sum, off, 64);
    float inv = sum > 0.f ? 1.f / sum : 0.f;
    for (int i = 0; i < 8; ++i) {
        f32x4 wv = v[i];
        for (int jj = 0; jj < 4; ++jj) wv[jj] *= inv;
        reinterpret_cast<f32x4*>(Pr)[(i << 6) + lane] = wv;
    }
}

__global__ __launch_bounds__(256) void pv_fallback_kernel(
    const float* __restrict__ P, const float* __restrict__ V, float* __restrict__ O)
{
    __shared__ unsigned short Ws[64 * 64];
    const int b  = blockIdx.y;
    const int m0 = blockIdx.x << 6;
    const int t  = threadIdx.x, lane = t & 63, wid = t >> 6;
    const int wr = wid >> 1, wc = wid & 1;
    const int lr = lane & 15, lg = lane >> 4;
    const float* Pg = P + ((size_t)b * SS + m0) * SS;
    f32x4 acc[2][4] = {};
    for (int k0 = 0; k0 < SS; k0 += 64) {
        __syncthreads();
        for (int i = 0; i < 4; ++i) {
            int f4  = (i << 8) + t;
            int row = f4 >> 4;
            int col = (f4 & 15) << 2;
            f32x4 wv = *reinterpret_cast<const f32x4*>(Pg + (size_t)row * SS + k0 + col);
            us4 h;
            for (int jj = 0; jj < 4; ++jj) h[jj] = f2bf(wv[jj]);
            *reinterpret_cast<us4*>(&Ws[swzB(row, col)]) = h;
        }
        __syncthreads();
        for (int kk = 0; kk < 64; kk += 32) {
            short8 a[2], bv[4];
            int kcol = kk + (lg << 3);
            for (int m = 0; m < 2; ++m)
                a[m] = *reinterpret_cast<const short8*>(&Ws[swzB((wr << 5) + (m << 4) + lr, kcol)]);
            for (int n = 0; n < 4; ++n) {
                int col = (wc << 6) + (n << 4) + lr;
                const float* vp = V + ((size_t)b * SS + k0 + kcol) * DD + col;
                short8 x;
                for (int jj = 0; jj < 8; ++jj) x[jj] = (short)f2bf(vp[(size_t)jj * DD]);
                bv[n] = x;
            }
            for (int m = 0; m < 2; ++m)
                for (int n = 0; n < 4; ++n)
                    acc[m][n] = __builtin_amdgcn_mfma_f32_16x16x32_bf16(a[m], bv[n], acc[m][n], 0, 0, 0);
        }
    }
    float* Og = O + ((size_t)b * SS + m0) * DD;
    for (int m = 0; m < 2; ++m)
        for (int n = 0; n < 4; ++n)
            for (int r = 0; r < 4; ++r)
                Og[(size_t)((wr << 5) + (m << 4) + (lg << 2) + r) * DD
                   + (wc << 6) + (n << 4) + lr] = acc[m][n][r];
}

// ---------------------------------------------------------------------------
extern "C" void kernel_launch(void* const* d_in, const int* in_sizes, int n_in,
                              void* d_out, int out_size, void* d_ws, size_t ws_size,
                              hipStream_t stream)
{
    const float* Q  = (const float*)d_in[0];
    const float* K  = (const float*)d_in[1];
    const float* V  = (const float*)d_in[2];
    const int* mask = (const int*)d_in[3];
    float* O = (float*)d_out;
    float* P = O + (size_t)BB * SS * DD;

    const size_t nE = (size_t)BB * SS * DD;   // 4194304 elements per tensor
    const size_t need = 2 * nE * sizeof(unsigned short)
                      + (size_t)BB * SS * sizeof(float) + 256;

    if (ws_size >= need) {
        unsigned short* Kb = (unsigned short*)d_ws;
        unsigned short* VT = Kb + nE;
        float* maskAdd = (float*)(VT + nE);

        prep_kernel<<<dim3(SS / 64, BB), 256, 0, stream>>>(K, V, mask, Kb, VT, maskAdd);
        fused16_kernel<<<512, 512, 0, stream>>>(Q, Kb, VT, maskAdd, O, P);
    } else {
        qk_exp_kernel<<<dim3(SS / 128, SS / 128, BB), 256, 0, stream>>>(Q, K, mask, P);
        norm_kernel<<<(BB * SS) / 4, 256, 0, stream>>>(P);
        pv_fallback_kernel<<<dim3(SS / 64, BB), 256, 0, stream>>>(P, V, O);
    }
}

// Round 16
// 129.853 us; speedup vs baseline: 1.0260x; 1.0260x over previous
//
#include <hip/hip_runtime.h>

#define BB 16
#define SS 2048
#define DD 128
// exp(s/sqrt(128)) = 2^(s * CE),  CE = log2(e)/sqrt(128)
#define CE (0.08838834764831845f * 1.4426950408889634f)

typedef __attribute__((ext_vector_type(4))) float f32x4;
typedef __attribute__((ext_vector_type(8))) short short8;
typedef __attribute__((ext_vector_type(4))) unsigned short us4;
typedef __attribute__((ext_vector_type(8))) unsigned short us8;

__device__ inline unsigned short f2bf(float f) {
    unsigned u = __float_as_uint(f);
    u += 0x7fffu + ((u >> 16) & 1u);   // round-to-nearest-even
    return (unsigned short)(u >> 16);
}

// XOR swizzles (swzA: 256B rows; swzB: 128B rows)
__device__ inline int swzA(int row, int col) {
    int byteoff = (row << 8) + ((col >> 3) << 4);
    byteoff ^= (row & 7) << 4;
    return (byteoff >> 1) + (col & 7);
}
__device__ inline int swzB(int row, int col) {
    int byteoff = (row << 7) + ((col >> 3) << 4);
    byteoff ^= (row & 7) << 4;
    return (byteoff >> 1) + (col & 7);
}

// ---------------------------------------------------------------------------
// prep: K fp32 -> bf16 Kb; V fp32 -> VT (b,d,k) bf16; mask -> additive fp32.
// (Q stays fp32; converted in fused8 at fragment load — read once per pass,
//  no staging amplification. K must be bf16: it is staged 64x per block.)
// ---------------------------------------------------------------------------
__global__ __launch_bounds__(256) void prep_kernel(
    const float* __restrict__ K, const float* __restrict__ V,
    const int* __restrict__ mask,
    unsigned short* __restrict__ Kb, unsigned short* __restrict__ VT,
    float* __restrict__ maskAdd)
{
    __shared__ unsigned short tile[64 * 136];
    int b = blockIdx.y, k0 = blockIdx.x << 6;
    int t = threadIdx.x;
    const size_t base = ((size_t)b * SS + k0) * DD;   // 8192 elements

    // K convert (contiguous)
    for (int i = 0; i < 8; ++i) {
        int f4 = (i << 8) + t;
        f32x4 k = reinterpret_cast<const f32x4*>(K + base)[f4];
        us4 kh;
        for (int j = 0; j < 4; ++j) kh[j] = f2bf(k[j]);
        reinterpret_cast<us4*>(Kb + base)[f4] = kh;
    }
    if (t < 64)
        maskAdd[(size_t)b * SS + k0 + t] =
            mask[(size_t)b * SS + k0 + t] ? 0.0f : __int_as_float(0xff800000);

    // V transpose
    for (int i = 0; i < 8; ++i) {
        int f4 = (i << 8) + t;
        int k  = f4 >> 5;
        int n  = (f4 & 31) << 2;
        f32x4 v = reinterpret_cast<const f32x4*>(V + base)[f4];
        us4 h;
        for (int j = 0; j < 4; ++j) h[j] = f2bf(v[j]);
        *reinterpret_cast<us4*>(&tile[k * 136 + n]) = h;
    }
    __syncthreads();
    unsigned short* outp = VT + (size_t)b * DD * SS;
    for (int i = 0; i < 4; ++i) {
        int id = (i << 8) + t;
        int n  = id >> 3;
        int c8 = id & 7;
        us8 o;
        for (int j = 0; j < 8; ++j) o[j] = tile[((c8 << 3) + j) * 136 + n];
        *reinterpret_cast<us8*>(&outp[(size_t)n * SS + k0 + (c8 << 3)]) = o;
    }
}

// ---------------------------------------------------------------------------
// fused8: block = (b, 128 q-rows), full KV. 512 thr = 8 waves in 4x2 (wq,wkv).
// grid 256 (1 block/CU, XCD batch-grouped). Q read fp32 + f2bf at load;
// K staged bf16 from Kb. Pass A: quadrant flash; epilogue cross-wave reduce;
// pass B: bit-identical S recompute, stream P.
// ---------------------------------------------------------------------------
__global__ __launch_bounds__(512, 2) void fused8_kernel(
    const float* __restrict__ Qf, const unsigned short* __restrict__ Kb,
    const unsigned short* __restrict__ VT, const float* __restrict__ maskAdd,
    float* __restrict__ O, float* __restrict__ P)
{
    __shared__ unsigned short Ks[2][64 * 128];    // 32 KB (reused as xch floats)
    __shared__ unsigned short VTs[2][128 * 64];   // 32 KB
    __shared__ unsigned short Ps[8 * 1024];       // 16 KB: per-wave 16r x 64c
    __shared__ float Lhalf[4][32];
    __shared__ float Larr[128];

    const int id = blockIdx.x;                    // grid 256
    const int xcd = id & 7, j = id >> 3;          // j in 0..31
    const int b   = (xcd << 1) | (j >> 4);
    const int q0  = (j & 15) << 7;                // 128-row q panel

    const int t = threadIdx.x, lane = t & 63, w = t >> 6;
    const int wq = w >> 1, wkv = w & 1;
    const int lr = lane & 15, lg = lane >> 4;

    const unsigned short* Kbb = Kb + (size_t)b * SS * DD;
    const unsigned short* Vbb = VT + (size_t)b * DD * SS;
    const float* Mb = maskAdd + (size_t)b * SS;

    // Pass-A Q fragments (B-operand): q = q0 + wq*32 + m*16 + lr  (fp32->bf16)
    const float* Qp = Qf + ((size_t)b * SS + q0 + wq * 32) * DD;
    short8 qf[2][4];
    for (int m = 0; m < 2; ++m)
        for (int kb = 0; kb < 4; ++kb) {
            const float* p = Qp + (size_t)(m * 16 + lr) * DD + kb * 32 + lg * 8;
            f32x4 a0 = *reinterpret_cast<const f32x4*>(p);
            f32x4 a1 = *(reinterpret_cast<const f32x4*>(p) + 1);
            short8 s;
            for (int jj = 0; jj < 4; ++jj) { s[jj] = (short)f2bf(a0[jj]); s[4 + jj] = (short)f2bf(a1[jj]); }
            qf[m][kb] = s;
        }

    f32x4 oacc[2][8] = {};
    float rsum[2] = {0.f, 0.f};
    unsigned short* Pw = &Ps[w * 1024];

    us8 kstg[2], vstg[2];
#define LOADTILE(kv)                                                             \
    for (int i = 0; i < 2; ++i) {                                                \
        int f = i * 512 + t;                                                     \
        kstg[i] = *reinterpret_cast<const us8*>(                                 \
            Kbb + (size_t)((kv) + (f >> 4)) * DD + ((f & 15) << 3));             \
        vstg[i] = *reinterpret_cast<const us8*>(                                 \
            Vbb + (size_t)(f >> 3) * SS + (kv) + ((f & 7) << 3));                \
    }
#define WRITETILE(bf)                                                            \
    for (int i = 0; i < 2; ++i) {                                                \
        int f = i * 512 + t;                                                     \
        *reinterpret_cast<us8*>(&Ks[bf][swzA(f >> 4, (f & 15) << 3)]) = kstg[i]; \
        *reinterpret_cast<us8*>(&VTs[bf][swzB(f >> 3, (f & 7) << 3)]) = vstg[i]; \
    }
#define LOADK(kv)                                                                \
    for (int i = 0; i < 2; ++i) {                                                \
        int f = i * 512 + t;                                                     \
        kstg[i] = *reinterpret_cast<const us8*>(                                 \
            Kbb + (size_t)((kv) + (f >> 4)) * DD + ((f & 15) << 3));             \
    }
#define WRITEK(bf)                                                               \
    for (int i = 0; i < 2; ++i) {                                                \
        int f = i * 512 + t;                                                     \
        *reinterpret_cast<us8*>(&Ks[bf][swzA(f >> 4, (f & 15) << 3)]) = kstg[i]; \
    }

    // ---------------- pass A ----------------
    LOADTILE(0);
    WRITETILE(0);

    for (int kt = 0; kt < 32; ++kt) {
        const int cur = kt & 1;
        const int kv0 = kt << 6;
        if (kt + 1 < 32) { LOADTILE(kv0 + 64); }   // T14
        __syncthreads();                           // buf[cur] visible

        // S^T quadrant: rows kv = wkv*32 + n*16 + lg*4 + r, cols q = m*16+lr
        f32x4 sacc[2][2] = {};
        __builtin_amdgcn_s_setprio(1);
        for (int kb = 0; kb < 4; ++kb) {
            short8 kf[2];
            for (int n = 0; n < 2; ++n)
                kf[n] = *reinterpret_cast<const short8*>(
                    &Ks[cur][swzA(wkv * 32 + n * 16 + lr, kb * 32 + lg * 8)]);
            for (int n = 0; n < 2; ++n)
                for (int m = 0; m < 2; ++m)
                    sacc[m][n] = __builtin_amdgcn_mfma_f32_16x16x32_bf16(
                        kf[n], qf[m][kb], sacc[m][n], 0, 0, 0);
        }
        __builtin_amdgcn_s_setprio(0);

        // p = 2^(s*CE + ma); rowsum; stash P[q=m*16+lr][kv_local] at (lr, m*32+kv)
        for (int n = 0; n < 2; ++n) {
            f32x4 ma = *reinterpret_cast<const f32x4*>(
                Mb + kv0 + wkv * 32 + n * 16 + lg * 4);
            for (int m = 0; m < 2; ++m) {
                us4 hh;
                for (int r = 0; r < 4; ++r) {
                    float p = __builtin_amdgcn_exp2f(fmaf(sacc[m][n][r], CE, ma[r]));
                    rsum[m] += p;
                    hh[r] = f2bf(p);
                }
                *reinterpret_cast<us4*>(&Pw[swzB(lr, m * 32 + n * 16 + lg * 4)]) = hh;
            }
        }
        asm volatile("s_waitcnt lgkmcnt(0)" ::: "memory");
        __builtin_amdgcn_sched_barrier(0);

        // PV over the 32-kv quadrant (single K=32 step)
        short8 pf[2];
        for (int m = 0; m < 2; ++m)
            pf[m] = *reinterpret_cast<const short8*>(&Pw[swzB(lr, m * 32 + lg * 8)]);
        __builtin_amdgcn_s_setprio(1);
        for (int nd = 0; nd < 8; ++nd) {
            short8 vf = *reinterpret_cast<const short8*>(
                &VTs[cur][swzB(nd * 16 + lr, wkv * 32 + lg * 8)]);
            for (int m = 0; m < 2; ++m)
                oacc[m][nd] = __builtin_amdgcn_mfma_f32_16x16x32_bf16(
                    pf[m], vf, oacc[m][nd], 0, 0, 0);
        }
        __builtin_amdgcn_s_setprio(0);

        if (kt + 1 < 32) { WRITETILE(cur ^ 1); }   // readers passed top barrier
    }

    // ---------------- epilogue: cross-wave reduce + O write ----------------
    for (int m = 0; m < 2; ++m) {   // sum over lg groups (q = ... + lr)
        rsum[m] += __shfl_xor(rsum[m], 16, 64);
        rsum[m] += __shfl_xor(rsum[m], 32, 64);
    }
    __syncthreads();   // pass A fully done; Ks reusable as xch
    if (wkv == 1 && lg == 0)
        for (int m = 0; m < 2; ++m) Lhalf[wq][m * 16 + lr] = rsum[m];
    __syncthreads();
    if (wkv == 0) {
        for (int m = 0; m < 2; ++m) {
            float L = rsum[m] + Lhalf[wq][m * 16 + lr];
            if (lg == 0) Larr[wq * 32 + m * 16 + lr] = L;
        }
    }
    // oacc exchange in 2 rounds through the Ks region (32 KB = 8192 floats)
    float* xch = reinterpret_cast<float*>(&Ks[0][0]);
    for (int round = 0; round < 2; ++round) {
        __syncthreads();
        if (wkv == 1 && (wq >> 1) == round)
            for (int m = 0; m < 2; ++m)
                for (int nd = 0; nd < 8; ++nd)
                    for (int r = 0; r < 4; ++r)
                        xch[(wq & 1) * 4096 + (m * 16 + lg * 4 + r) * 128 + nd * 16 + lr]
                            = oacc[m][nd][r];
        __syncthreads();
        if (wkv == 0 && (wq >> 1) == round)
            for (int m = 0; m < 2; ++m)
                for (int nd = 0; nd < 8; ++nd)
                    for (int r = 0; r < 4; ++r)
                        oacc[m][nd][r] +=
                            xch[(wq & 1) * 4096 + (m * 16 + lg * 4 + r) * 128 + nd * 16 + lr];
    }
    __syncthreads();   // Larr + exchange complete
    if (wkv == 0) {
        float* Og = O + ((size_t)b * SS + q0 + wq * 32) * DD;
        float inv[2][4];
        for (int m = 0; m < 2; ++m)
            for (int r = 0; r < 4; ++r) {
                float L = Larr[wq * 32 + m * 16 + lg * 4 + r];
                inv[m][r] = L > 0.f ? 1.f / L : 0.f;
            }
        for (int m = 0; m < 2; ++m)
            for (int nd = 0; nd < 8; ++nd)
                for (int r = 0; r < 4; ++r)
                    Og[(size_t)(m * 16 + lg * 4 + r) * DD + nd * 16 + lr]
                        = oacc[m][nd][r] * inv[m][r];
    }
    __syncthreads();

    // pass-B per-row lil (q = w*16 + lr)
    float Lq = Larr[w * 16 + lr];
    const float lil = Lq > 0.f ? -__builtin_amdgcn_logf(Lq)
                               : __int_as_float(0xff800000);
    short8 qf2[4];
    {
        const float* Qp2 = Qf + ((size_t)b * SS + q0 + w * 16 + lr) * DD;
        for (int kb = 0; kb < 4; ++kb) {
            const float* p = Qp2 + kb * 32 + lg * 8;
            f32x4 a0 = *reinterpret_cast<const f32x4*>(p);
            f32x4 a1 = *(reinterpret_cast<const f32x4*>(p) + 1);
            short8 s;
            for (int jj = 0; jj < 4; ++jj) { s[jj] = (short)f2bf(a0[jj]); s[4 + jj] = (short)f2bf(a1[jj]); }
            qf2[kb] = s;
        }
    }

    // ---------------- pass B ----------------
    LOADK(0);
    WRITEK(0);   // safe: all exchange reads done before last barrier

    for (int kt = 0; kt < 32; ++kt) {
        const int cur = kt & 1;
        const int kv0 = kt << 6;
        if (kt + 1 < 32) { LOADK(kv0 + 64); }
        __syncthreads();

        // identical per-(q,kv) kb-chain as pass A -> bit-identical S
        f32x4 sacc2[4] = {};
        for (int kb = 0; kb < 4; ++kb) {
            short8 kf[4];
            for (int n = 0; n < 4; ++n)
                kf[n] = *reinterpret_cast<const short8*>(
                    &Ks[cur][swzA(n * 16 + lr, kb * 32 + lg * 8)]);
            for (int n = 0; n < 4; ++n)
                sacc2[n] = __builtin_amdgcn_mfma_f32_16x16x32_bf16(
                    kf[n], qf2[kb], sacc2[n], 0, 0, 0);
        }

        float* Pp = P + ((size_t)b * SS + q0 + w * 16 + lr) * SS + kv0;
        for (int n = 0; n < 4; ++n) {
            f32x4 ma = *reinterpret_cast<const f32x4*>(Mb + kv0 + n * 16 + lg * 4);
            f32x4 out;
            for (int r = 0; r < 4; ++r)
                out[r] = __builtin_amdgcn_exp2f(fmaf(sacc2[n][r], CE, ma[r]) + lil);
            *reinterpret_cast<f32x4*>(Pp + n * 16 + lg * 4) = out;
        }

        if (kt + 1 < 32) { WRITEK(cur ^ 1); }
    }
#undef LOADTILE
#undef WRITETILE
#undef LOADK
#undef WRITEK
}

// ---------------------------------------------------------------------------
// Fallback pipeline (no workspace requirements)
// ---------------------------------------------------------------------------
__global__ __launch_bounds__(256) void qk_exp_kernel(
    const float* __restrict__ Q, const float* __restrict__ Kin,
    const int* __restrict__ mask, float* __restrict__ P)
{
    __shared__ unsigned short Qs[128 * 128];
    __shared__ unsigned short Ks[128 * 128];
    const int b  = blockIdx.z;
    const int m0 = blockIdx.y << 7;
    const int n0 = blockIdx.x << 7;
    const int t  = threadIdx.x;
    const float* Qp = Q   + ((size_t)b * SS + m0) * DD;
    const float* Kp = Kin + ((size_t)b * SS + n0) * DD;
    for (int i = 0; i < 16; ++i) {
        int f4  = (i << 8) + t;
        int row = f4 >> 5;
        int col = (f4 & 31) << 2;
        f32x4 q = reinterpret_cast<const f32x4*>(Qp)[f4];
        f32x4 k = reinterpret_cast<const f32x4*>(Kp)[f4];
        us4 qh, kh;
        for (int jj = 0; jj < 4; ++jj) { qh[jj] = f2bf(q[jj]); kh[jj] = f2bf(k[jj]); }
        *reinterpret_cast<us4*>(&Qs[swzA(row, col)]) = qh;
        *reinterpret_cast<us4*>(&Ks[swzA(row, col)]) = kh;
    }
    __syncthreads();
    const int lane = t & 63, wid = t >> 6;
    const int wr = wid >> 1, wc = wid & 1;
    const int lr = lane & 15, lg = lane >> 4;
    f32x4 acc[4][4] = {};
    for (int kb = 0; kb < 4; ++kb) {
        short8 a[4], bq[4];
        int kcol = (kb << 5) + (lg << 3);
        for (int m = 0; m < 4; ++m)
            a[m] = *reinterpret_cast<const short8*>(&Qs[swzA((wr << 6) + (m << 4) + lr, kcol)]);
        for (int n = 0; n < 4; ++n)
            bq[n] = *reinterpret_cast<const short8*>(&Ks[swzA((wc << 6) + (n << 4) + lr, kcol)]);
        for (int m = 0; m < 4; ++m)
            for (int n = 0; n < 4; ++n)
                acc[m][n] = __builtin_amdgcn_mfma_f32_16x16x32_bf16(a[m], bq[n], acc[m][n], 0, 0, 0);
    }
    const int* am = mask + (size_t)b * SS;
    for (int n = 0; n < 4; ++n) {
        int col = n0 + (wc << 6) + (n << 4) + lr;
        bool allow = am[col] != 0;
        for (int m = 0; m < 4; ++m) {
            int rowb = m0 + (wr << 6) + (m << 4) + (lg << 2);
            float* Pp = P + ((size_t)b * SS + rowb) * SS + col;
            for (int r = 0; r < 4; ++r) {
                float p = allow ? __expf(acc[m][n][r] * 0.08838834764831845f) : 0.0f;
                Pp[(size_t)r * SS] = p;
            }
        }
    }
}

__global__ __launch_bounds__(256) void norm_kernel(float* __restrict__ P)
{
    int row  = (blockIdx.x << 2) + (threadIdx.x >> 6);
    int lane = threadIdx.x & 63;
    float* Pr = P + (size_t)row * SS;
    f32x4 v[8];
    float sum = 0.f;
    for (int i = 0; i < 8; ++i) {
        v[i] = reinterpret_cast<f32x4*>(Pr)[(i << 6) + lane];
        sum += v[i][0] + v[i][1] + v[i][2] + v[i][3];
    }
    for (int off = 1; off < 64; off <<= 1) sum += __shfl_xor(sum, off, 64);
    float inv = sum > 0.f ? 1.f / sum : 0.f;
    for (int i = 0; i < 8; ++i) {
        f32x4 wv = v[i];
        for (int jj = 0; jj < 4; ++jj) wv[jj] *= inv;
        reinterpret_cast<f32x4*>(Pr)[(i << 6) + lane] = wv;
    }
}

__global__ __launch_bounds__(256) void pv_fallback_kernel(
    const float* __restrict__ P, const float* __restrict__ V, float* __restrict__ O)
{
    __shared__ unsigned short Ws[64 * 64];
    const int b  = blockIdx.y;
    const int m0 = blockIdx.x << 6;
    const int t  = threadIdx.x, lane = t & 63, wid = t >> 6;
    const int wr = wid >> 1, wc = wid & 1;
    const int lr = lane & 15, lg = lane >> 4;
    const float* Pg = P + ((size_t)b * SS + m0) * SS;
    f32x4 acc[2][4] = {};
    for (int k0 = 0; k0 < SS; k0 += 64) {
        __syncthreads();
        for (int i = 0; i < 4; ++i) {
            int f4  = (i << 8) + t;
            int row = f4 >> 4;
            int col = (f4 & 15) << 2;
            f32x4 wv = *reinterpret_cast<const f32x4*>(Pg + (size_t)row * SS + k0 + col);
            us4 h;
            for (int jj = 0; jj < 4; ++jj) h[jj] = f2bf(wv[jj]);
            *reinterpret_cast<us4*>(&Ws[swzB(row, col)]) = h;
        }
        __syncthreads();
        for (int kk = 0; kk < 64; kk += 32) {
            short8 a[2], bv[4];
            int kcol = kk + (lg << 3);
            for (int m = 0; m < 2; ++m)
                a[m] = *reinterpret_cast<const short8*>(&Ws[swzB((wr << 5) + (m << 4) + lr, kcol)]);
            for (int n = 0; n < 4; ++n) {
                int col = (wc << 6) + (n << 4) + lr;
                const float* vp = V + ((size_t)b * SS + k0 + kcol) * DD + col;
                short8 x;
                for (int jj = 0; jj < 8; ++jj) x[jj] = (short)f2bf(vp[(size_t)jj * DD]);
                bv[n] = x;
            }
            for (int m = 0; m < 2; ++m)
                for (int n = 0; n < 4; ++n)
                    acc[m][n] = __builtin_amdgcn_mfma_f32_16x16x32_bf16(a[m], bv[n], acc[m][n], 0, 0, 0);
        }
    }
    float* Og = O + ((size_t)b * SS + m0) * DD;
    for (int m = 0; m < 2; ++m)
        for (int n = 0; n < 4; ++n)
            for (int r = 0; r < 4; ++r)
                Og[(size_t)((wr << 5) + (m << 4) + (lg << 2) + r) * DD
                   + (wc << 6) + (n << 4) + lr] = acc[m][n][r];
}

// ---------------------------------------------------------------------------
extern "C" void kernel_launch(void* const* d_in, const int* in_sizes, int n_in,
                              void* d_out, int out_size, void* d_ws, size_t ws_size,
                              hipStream_t stream)
{
    const float* Q  = (const float*)d_in[0];
    const float* K  = (const float*)d_in[1];
    const float* V  = (const float*)d_in[2];
    const int* mask = (const int*)d_in[3];
    float* O = (float*)d_out;
    float* P = O + (size_t)BB * SS * DD;

    const size_t nE = (size_t)BB * SS * DD;   // 4194304 elements per tensor
    const size_t need = 2 * nE * sizeof(unsigned short)
                      + (size_t)BB * SS * sizeof(float) + 256;

    if (ws_size >= need) {
        unsigned short* Kb = (unsigned short*)d_ws;
        unsigned short* VT = Kb + nE;
        float* maskAdd = (float*)(VT + nE);

        prep_kernel<<<dim3(SS / 64, BB), 256, 0, stream>>>(K, V, mask, Kb, VT, maskAdd);
        fused8_kernel<<<256, 512, 0, stream>>>(Q, Kb, VT, maskAdd, O, P);
    } else {
        qk_exp_kernel<<<dim3(SS / 128, SS / 128, BB), 256, 0, stream>>>(Q, K, mask, P);
        norm_kernel<<<(BB * SS) / 4, 256, 0, stream>>>(P);
        pv_fallback_kernel<<<dim3(SS / 64, BB), 256, 0, stream>>>(P, V, O);
    }
}